// Round 4
// baseline (207.086 us; speedup 1.0000x reference)
//
#include <hip/hip_runtime.h>
#include <cstdint>
#include <cstddef>

#define SEQL   2048
#define DMODEL 1024
#define NHEADS 16
#define DHEAD  64
#define MROWS  4096   // BATCH * SEQ

typedef __attribute__((ext_vector_type(8))) short short8;   // 8 bf16 (4 VGPRs)
typedef __attribute__((ext_vector_type(4))) float f32x4;    // MFMA 16x16 C/D
typedef __attribute__((ext_vector_type(4))) unsigned int u32x4;

__device__ __forceinline__ unsigned short f2bf(float x) {
  unsigned int u = __float_as_uint(x);
  u += 0x7fffu + ((u >> 16) & 1u);   // round-to-nearest-even
  return (unsigned short)(u >> 16);
}
__device__ __forceinline__ float bf2f(unsigned short u) {
  return __uint_as_float(((unsigned int)u) << 16);
}
// pack two f32 -> 2xbf16 in one VGPR (RNE); no builtin on gfx950 -> asm
__device__ __forceinline__ unsigned int cvtpk(float lo, float hi) {
  unsigned int r;
  asm("v_cvt_pk_bf16_f32 %0, %1, %2" : "=v"(r) : "v"(lo), "v"(hi));
  return r;
}
// load 8 contiguous fp32, round to 8 bf16
__device__ __forceinline__ short8 cvt8(const float* __restrict__ p) {
  const float4 lo = *(const float4*)p;
  const float4 hi = *(const float4*)(p + 4);
  short8 v;
  v[0] = (short)f2bf(lo.x); v[1] = (short)f2bf(lo.y);
  v[2] = (short)f2bf(lo.z); v[3] = (short)f2bf(lo.w);
  v[4] = (short)f2bf(hi.x); v[5] = (short)f2bf(hi.y);
  v[6] = (short)f2bf(hi.z); v[7] = (short)f2bf(hi.w);
  return v;
}
// async global->LDS, 16B per lane; lds base must be wave-uniform
__device__ __forceinline__ void gload_lds16(const unsigned short* g, unsigned short* l) {
  __builtin_amdgcn_global_load_lds(
      (const __attribute__((address_space(1))) unsigned int*)g,
      (__attribute__((address_space(3))) unsigned int*)l, 16, 0, 0);
}

// ---------------------------------------------------------------------------
// One-shot fp32 -> bf16 conversion of x and the four weight matrices.
// ---------------------------------------------------------------------------
__global__ __launch_bounds__(256) void cvt_bf16(
    const float* __restrict__ x,  const float* __restrict__ wq,
    const float* __restrict__ wk, const float* __restrict__ wv,
    const float* __restrict__ wo,
    unsigned short* __restrict__ xb,  unsigned short* __restrict__ wqb,
    unsigned short* __restrict__ wkb, unsigned short* __restrict__ wvb,
    unsigned short* __restrict__ wob) {
  const int y = blockIdx.y;
  const float* src; unsigned short* dst;
  if (y < 4)       { src = x + ((size_t)y << 20); dst = xb + ((size_t)y << 20); }
  else if (y == 4) { src = wq; dst = wqb; }
  else if (y == 5) { src = wk; dst = wkb; }
  else if (y == 6) { src = wv; dst = wvb; }
  else             { src = wo; dst = wob; }
  const size_t i = ((size_t)blockIdx.x * 256 + threadIdx.x) * 8;
  *(short8*)(dst + i) = cvt8(src + i);
}

// ---------------------------------------------------------------------------
// QKV projection, all-bf16, async staging (m97-style).
// z=0 -> Q bf16; z=1 -> K bf16; z=2 -> V transposed into Vt.
// ---------------------------------------------------------------------------
__global__ __launch_bounds__(256) void gemm_qkv(
    const unsigned short* __restrict__ A,
    const unsigned short* __restrict__ W0, const unsigned short* __restrict__ W1,
    const unsigned short* __restrict__ W2,
    unsigned short* __restrict__ C0, unsigned short* __restrict__ C1,
    unsigned short* __restrict__ Vt,
    int Mda, int Nda, int Kda) {
  const unsigned short* W;
  if (blockIdx.z == 0)      W = W0;
  else if (blockIdx.z == 1) W = W1;
  else                      W = W2;

  __shared__ __attribute__((aligned(16))) unsigned short As[128 * 32];
  __shared__ __attribute__((aligned(16))) unsigned short Bs[128 * 32];

  const int t = threadIdx.x;
  const int m0 = blockIdx.y * 128, n0 = blockIdx.x * 128;
  const int w = t >> 6, lane = t & 63;
  const int l15 = lane & 15, quad = lane >> 4;
  const int wm = (w >> 1) * 64, wn = (w & 1) * 64;

  const int r1 = t >> 2,         c1 = (t & 3) * 8;
  const int r2 = (t + 256) >> 2, c2 = (t & 3) * 8;
  unsigned short* asd1 = As + (size_t)(w << 6) * 8;
  unsigned short* asd2 = As + (size_t)(256 + (w << 6)) * 8;
  unsigned short* bsd1 = Bs + (size_t)(w << 6) * 8;
  unsigned short* bsd2 = Bs + (size_t)(256 + (w << 6)) * 8;

  f32x4 acc[4][4] = {};

  for (int k0 = 0; k0 < Kda; k0 += 32) {
    __syncthreads();
    gload_lds16(A + (size_t)(m0 + r1) * Kda + k0 + c1, asd1);
    gload_lds16(A + (size_t)(m0 + r2) * Kda + k0 + c2, asd2);
    gload_lds16(W + (size_t)(n0 + r1) * Kda + k0 + c1, bsd1);
    gload_lds16(W + (size_t)(n0 + r2) * Kda + k0 + c2, bsd2);
    __syncthreads();

    short8 af[4], bfr[4];
#pragma unroll
    for (int i = 0; i < 4; ++i)
      af[i] = *(const short8*)(&As[(wm + i * 16 + l15) * 32 + quad * 8]);
#pragma unroll
    for (int j = 0; j < 4; ++j)
      bfr[j] = *(const short8*)(&Bs[(wn + j * 16 + l15) * 32 + quad * 8]);
#pragma unroll
    for (int i = 0; i < 4; ++i)
#pragma unroll
      for (int j = 0; j < 4; ++j)
        acc[i][j] = __builtin_amdgcn_mfma_f32_16x16x32_bf16(af[i], bfr[j], acc[i][j], 0, 0, 0);
  }

  if (blockIdx.z != 2) {
    unsigned short* C = (blockIdx.z == 0) ? C0 : C1;
#pragma unroll
    for (int i = 0; i < 4; ++i)
#pragma unroll
      for (int j = 0; j < 4; ++j)
#pragma unroll
        for (int r = 0; r < 4; ++r) {
          int row = m0 + wm + i * 16 + quad * 4 + r;
          int col = n0 + wn + j * 16 + l15;
          C[(size_t)row * Nda + col] = f2bf(acc[i][j][r]);
        }
  } else {
    // V transposed write: 4 consecutive s-values per 8B store
#pragma unroll
    for (int i = 0; i < 4; ++i) {
      const int srow = m0 + wm + i * 16 + quad * 4;   // b*SEQL + s (s%4==0)
      const int bq = srow >> 11, s = srow & (SEQL - 1);
#pragma unroll
      for (int j = 0; j < 4; ++j) {
        const int col = n0 + wn + j * 16 + l15;       // h*64 + d
        ushort4 v;
        v.x = f2bf(acc[i][j][0]); v.y = f2bf(acc[i][j][1]);
        v.z = f2bf(acc[i][j][2]); v.w = f2bf(acc[i][j][3]);
        *(ushort4*)(Vt + ((size_t)(bq * DMODEL + col)) * SEQL + s) = v;
      }
    }
  }
}

// ---------------------------------------------------------------------------
// Output projection: A bf16 [M][K], W bf16 [N][K], C fp32 [M][N]
// ---------------------------------------------------------------------------
__global__ __launch_bounds__(256) void gemm_out(
    const unsigned short* __restrict__ A,
    const unsigned short* __restrict__ W,
    float* __restrict__ C,
    int Mda, int Nda, int Kda) {
  __shared__ __attribute__((aligned(16))) unsigned short As[128 * 32];
  __shared__ __attribute__((aligned(16))) unsigned short Bs[128 * 32];

  const int t = threadIdx.x;
  const int m0 = blockIdx.y * 128, n0 = blockIdx.x * 128;
  const int w = t >> 6, lane = t & 63;
  const int l15 = lane & 15, quad = lane >> 4;
  const int wm = (w >> 1) * 64, wn = (w & 1) * 64;

  const int r1 = t >> 2,         c1 = (t & 3) * 8;
  const int r2 = (t + 256) >> 2, c2 = (t & 3) * 8;
  unsigned short* asd1 = As + (size_t)(w << 6) * 8;
  unsigned short* asd2 = As + (size_t)(256 + (w << 6)) * 8;
  unsigned short* bsd1 = Bs + (size_t)(w << 6) * 8;
  unsigned short* bsd2 = Bs + (size_t)(256 + (w << 6)) * 8;

  f32x4 acc[4][4] = {};

  for (int k0 = 0; k0 < Kda; k0 += 32) {
    __syncthreads();
    gload_lds16(A + (size_t)(m0 + r1) * Kda + k0 + c1, asd1);
    gload_lds16(A + (size_t)(m0 + r2) * Kda + k0 + c2, asd2);
    gload_lds16(W + (size_t)(n0 + r1) * Kda + k0 + c1, bsd1);
    gload_lds16(W + (size_t)(n0 + r2) * Kda + k0 + c2, bsd2);
    __syncthreads();

    short8 af[4], bfr[4];
#pragma unroll
    for (int i = 0; i < 4; ++i)
      af[i] = *(const short8*)(&As[(wm + i * 16 + l15) * 32 + quad * 8]);
#pragma unroll
    for (int j = 0; j < 4; ++j)
      bfr[j] = *(const short8*)(&Bs[(wn + j * 16 + l15) * 32 + quad * 8]);
#pragma unroll
    for (int i = 0; i < 4; ++i)
#pragma unroll
      for (int j = 0; j < 4; ++j)
        acc[i][j] = __builtin_amdgcn_mfma_f32_16x16x32_bf16(af[i], bfr[j], acc[i][j], 0, 0, 0);
  }

#pragma unroll
  for (int i = 0; i < 4; ++i)
#pragma unroll
    for (int j = 0; j < 4; ++j)
#pragma unroll
      for (int r = 0; r < 4; ++r) {
        int row = m0 + wm + i * 16 + quad * 4 + r;
        int col = n0 + wn + j * 16 + l15;
        C[(size_t)row * Nda + col] = acc[i][j][r];
      }
}

// ---------------------------------------------------------------------------
// In-place RoPE on bf16 Q and K flat [M][1024].
// Q additionally pre-scaled by 1/sqrt(DHEAD)=0.125 (exact in bf16).
// ---------------------------------------------------------------------------
__global__ __launch_bounds__(256) void rope_inplace(unsigned short* __restrict__ Q,
                                                    unsigned short* __restrict__ K,
                                                    const int* __restrict__ pos_arr) {
  const int row = blockIdx.x;            // b*SEQ + s
  const int s = row & (SEQL - 1);
  const float pos = (float)pos_arr[s];
  // log2(10000)/32 = 0.4152410118609203
  for (int p = threadIdx.x; p < 512; p += 256) {
    const int h = p >> 5, i = p & 31;
    float inv = exp2f((float)i * -0.4152410118609203f);
    float ang = pos * inv;
    float sn, cs;
    sincosf(ang, &sn, &cs);
    size_t base = (size_t)row * DMODEL + h * DHEAD + 2 * i;
    float e = bf2f(Q[base]), o = bf2f(Q[base + 1]);
    Q[base]     = f2bf((e * cs - o * sn) * 0.125f);
    Q[base + 1] = f2bf((e * sn + o * cs) * 0.125f);
    e = bf2f(K[base]); o = bf2f(K[base + 1]);
    K[base]     = f2bf(e * cs - o * sn);
    K[base + 1] = f2bf(e * sn + o * cs);
  }
}

// exp + causal-mask + bf16-pack for one 16-q group over this kv64 tile.
// Produces bp0 (kv +0/+4 slices) and bp1 (kv +32/+36 slices), accumulates lp.
#define EXP_PACK(S1, S2, S3, S4, QW, QROW, BP0, BP1, LP)                      \
  {                                                                           \
    float p1[4], p2[4], p3[4], p4[4];                                         \
    if (kv0 + 63 <= (QW)) {                                                   \
      _Pragma("unroll") for (int r = 0; r < 4; ++r) {                         \
        p1[r] = __expf(S1[r]); p2[r] = __expf(S2[r]);                         \
        p3[r] = __expf(S3[r]); p4[r] = __expf(S4[r]);                         \
        LP += (p1[r] + p2[r]) + (p3[r] + p4[r]);                              \
      }                                                                       \
    } else {                                                                  \
      _Pragma("unroll") for (int r = 0; r < 4; ++r) {                         \
        const int kv1 = kv0 + 8 * quad + r;                                   \
        p1[r] = (kv1 > (QROW))      ? 0.f : __expf(S1[r]);                    \
        p2[r] = (kv1 + 4 > (QROW))  ? 0.f : __expf(S2[r]);                    \
        p3[r] = (kv1 + 32 > (QROW)) ? 0.f : __expf(S3[r]);                    \
        p4[r] = (kv1 + 36 > (QROW)) ? 0.f : __expf(S4[r]);                    \
        LP += (p1[r] + p2[r]) + (p3[r] + p4[r]);                              \
      }                                                                       \
    }                                                                         \
    u32x4 lo_, hi_;                                                           \
    lo_[0] = cvtpk(p1[0], p1[1]); lo_[1] = cvtpk(p1[2], p1[3]);               \
    lo_[2] = cvtpk(p2[0], p2[1]); lo_[3] = cvtpk(p2[2], p2[3]);               \
    hi_[0] = cvtpk(p3[0], p3[1]); hi_[1] = cvtpk(p3[2], p3[3]);               \
    hi_[2] = cvtpk(p4[0], p4[1]); hi_[3] = cvtpk(p4[2], p4[3]);               \
    BP0 = __builtin_bit_cast(short8, lo_);                                    \
    BP1 = __builtin_bit_cast(short8, hi_);                                    \
  }

// ---------------------------------------------------------------------------
// Causal attention, R5-verified transposed-MFMA math + R15:
//  R12/R13/R14 post-mortem: time tracks per-CU work, insensitive to
//  buffering/barriers/tile size -> LDS pipe (~60% busy: every wave reads the
//  FULL K+V tile; staging has zero dedup) is the throughput+queueing limiter.
//  R15: 32 q rows per wave (two 16-q groups A/B sharing the same K/V
//  fragment reads) -> LDS reads per unit work halved; MFMA per read doubled.
//  Block = 128 q rows; 512 single-phase blocks, 2/CU. Balance via the
//  R13-observed dispatch rule (CU ~ id mod 256): ids 0..255 get heavy qblks
//  (8+p8), ids 256..511 the complementary light (7-p8) with the SAME bh ->
//  per-CU trips sum to uniform 34 and both blocks share K/V in L2.
//  Dbuf + setprio + cvtpk kept.
// ---------------------------------------------------------------------------
__global__ __launch_bounds__(256, 2) void attn_kernel(const unsigned short* __restrict__ Kf,
                                                      const unsigned short* __restrict__ Vt,
                                                      unsigned short* __restrict__ Qio) {
  __shared__ __attribute__((aligned(16))) unsigned short Ks[2][4096];  // 2 x 8 KB
  __shared__ __attribute__((aligned(16))) unsigned short Vs[2][4096];  // 2 x 8 KB

  const int u  = blockIdx.x & 255;
  const int hi = blockIdx.x >> 8;               // 0: heavy half, 1: light half
  const int p8 = u >> 5;                        // 0..7
  const int bh = (((u >> 3) & 3) << 3) | (u & 7);   // 0..31, id&7 = XCD slot
  const int qblk = hi ? (7 - p8) : (8 + p8);    // complementary pairs per CU
  const int b = bh >> 4, h = bh & 15;
  const int w = threadIdx.x >> 6;
  const int lane = threadIdx.x & 63;
  const int l15 = lane & 15, quad = lane >> 4;

  // staging source addresses (lane-permuted so LDS slot = fragment layout)
  const int g = (w << 6) | lane;
  const int ktau = g >> 7, kseg = (g >> 4) & 7, km = g & 15;
  const int kvl = 8 * (km >> 2) + (km & 3) + 4 * ktau;
  const unsigned short* kstage = Kf + ((size_t)(b * SEQL + kvl)) * DMODEL + h * DHEAD + kseg * 8;
  const int vdb = (g >> 6) & 3, vq = (g >> 4) & 3, vm = g & 15;
  const unsigned short* vstage = Vt + ((size_t)(bh * DHEAD + vdb * 16 + vm)) * SEQL + vq * 8;
  const int dofs = (w << 6) * 8;   // per-wave LDS dest offset (shorts)

  // fragment read offset (shorts) within a 2048-short half
  const int rs = (l15 + (quad << 4)) << 3;

  const int Q0 = qblk << 7;            // 128 q rows per block
  const int qwA = Q0 + w * 16;         // group A: q rows [qwA, qwA+15]
  const int qwB = qwA + 64;            // group B: q rows [qwB, qwB+15]
  const int qrowA = qwA + l15;
  const int qrowB = qrowA + 64;

  // Q B-frags for both groups: n=l15 (q), k=8*quad+j (d)
  const unsigned short* qpA = Qio + ((size_t)(b * SEQL + qrowA)) * DMODEL + h * DHEAD + quad * 8;
  const unsigned short* qpB = Qio + ((size_t)(b * SEQL + qrowB)) * DMODEL + h * DHEAD + quad * 8;
  const short8 bqA0 = *(const short8*)(qpA);
  const short8 bqA1 = *(const short8*)(qpA + 32);
  const short8 bqB0 = *(const short8*)(qpB);
  const short8 bqB1 = *(const short8*)(qpB + 32);

  f32x4 oA0 = {0.f, 0.f, 0.f, 0.f}, oA1 = oA0, oA2 = oA0, oA3 = oA0;
  f32x4 oB0 = oA0, oB1 = oA0, oB2 = oA0, oB3 = oA0;
  float lpA = 0.f, lpB = 0.f;

  const int trips = 2 * qblk + 2;   // kv64 tiles covering kv < 128*(qblk+1)

  // prologue: stage tile 0 into buffer 0
  gload_lds16(kstage,                        &Ks[0][dofs]);
  gload_lds16(kstage + (size_t)32 * DMODEL,  &Ks[0][2048 + dofs]);
  gload_lds16(vstage,                        &Vs[0][dofs]);
  gload_lds16(vstage + 32,                   &Vs[0][2048 + dofs]);
  __syncthreads();   // drain prologue loads; all waves see tile 0

  int cur = 0;
#pragma unroll 1
  for (int t = 0; t < trips; ++t) {
    // prefetch next tile into the other buffer; in flight during compute
    if (t + 1 < trips) {
      const int kvn = (t + 1) * 64;
      gload_lds16(kstage + (size_t)kvn * DMODEL,        &Ks[cur ^ 1][dofs]);
      gload_lds16(kstage + (size_t)(kvn + 32) * DMODEL, &Ks[cur ^ 1][2048 + dofs]);
      gload_lds16(vstage + kvn,                         &Vs[cur ^ 1][dofs]);
      gload_lds16(vstage + kvn + 32,                    &Vs[cur ^ 1][2048 + dofs]);
    }
    const int kv0 = t * 64;

    // K fragments: read ONCE, feed BOTH q groups (halves LDS reads/work)
    const unsigned short* kb = &Ks[cur][0];
    const short8 k0 = *(const short8*)(kb + rs);
    const short8 k1 = *(const short8*)(kb + rs + 512);
    const short8 k2 = *(const short8*)(kb + rs + 1024);
    const short8 k3 = *(const short8*)(kb + rs + 1536);
    const short8 k4 = *(const short8*)(kb + 2048 + rs);
    const short8 k5 = *(const short8*)(kb + 2048 + rs + 512);
    const short8 k6 = *(const short8*)(kb + 2048 + rs + 1024);
    const short8 k7 = *(const short8*)(kb + 2048 + rs + 1536);
    const f32x4 z = {0.f, 0.f, 0.f, 0.f};
    f32x4 sA1, sA2, sA3, sA4, sB1, sB2, sB3, sB4;
    __builtin_amdgcn_s_setprio(1);
    sA1 = __builtin_amdgcn_mfma_f32_16x16x32_bf16(k0, bqA0, z, 0, 0, 0);
    sB1 = __builtin_amdgcn_mfma_f32_16x16x32_bf16(k0, bqB0, z, 0, 0, 0);
    sA1 = __builtin_amdgcn_mfma_f32_16x16x32_bf16(k1, bqA1, sA1, 0, 0, 0);
    sB1 = __builtin_amdgcn_mfma_f32_16x16x32_bf16(k1, bqB1, sB1, 0, 0, 0);
    sA2 = __builtin_amdgcn_mfma_f32_16x16x32_bf16(k2, bqA0, z, 0, 0, 0);
    sB2 = __builtin_amdgcn_mfma_f32_16x16x32_bf16(k2, bqB0, z, 0, 0, 0);
    sA2 = __builtin_amdgcn_mfma_f32_16x16x32_bf16(k3, bqA1, sA2, 0, 0, 0);
    sB2 = __builtin_amdgcn_mfma_f32_16x16x32_bf16(k3, bqB1, sB2, 0, 0, 0);
    sA3 = __builtin_amdgcn_mfma_f32_16x16x32_bf16(k4, bqA0, z, 0, 0, 0);
    sB3 = __builtin_amdgcn_mfma_f32_16x16x32_bf16(k4, bqB0, z, 0, 0, 0);
    sA3 = __builtin_amdgcn_mfma_f32_16x16x32_bf16(k5, bqA1, sA3, 0, 0, 0);
    sB3 = __builtin_amdgcn_mfma_f32_16x16x32_bf16(k5, bqB1, sB3, 0, 0, 0);
    sA4 = __builtin_amdgcn_mfma_f32_16x16x32_bf16(k6, bqA0, z, 0, 0, 0);
    sB4 = __builtin_amdgcn_mfma_f32_16x16x32_bf16(k6, bqB0, z, 0, 0, 0);
    sA4 = __builtin_amdgcn_mfma_f32_16x16x32_bf16(k7, bqA1, sA4, 0, 0, 0);
    sB4 = __builtin_amdgcn_mfma_f32_16x16x32_bf16(k7, bqB1, sB4, 0, 0, 0);
    __builtin_amdgcn_s_setprio(0);

    // exp (+causal mask) -> PV B-operands, per group (wave-uniform branches)
    short8 bpA0, bpA1, bpB0, bpB1;
    EXP_PACK(sA1, sA2, sA3, sA4, qwA, qrowA, bpA0, bpA1, lpA);
    EXP_PACK(sB1, sB2, sB3, sB4, qwB, qrowB, bpB0, bpB1, lpB);

    // V fragments: read ONCE, feed BOTH groups' PV
    const unsigned short* vb = &Vs[cur][0];
    const short8 v0 = *(const short8*)(vb + rs);
    const short8 v1 = *(const short8*)(vb + rs + 512);
    const short8 v2 = *(const short8*)(vb + rs + 1024);
    const short8 v3 = *(const short8*)(vb + rs + 1536);
    const short8 v4 = *(const short8*)(vb + 2048 + rs);
    const short8 v5 = *(const short8*)(vb + 2048 + rs + 512);
    const short8 v6 = *(const short8*)(vb + 2048 + rs + 1024);
    const short8 v7 = *(const short8*)(vb + 2048 + rs + 1536);
    __builtin_amdgcn_s_setprio(1);
    oA0 = __builtin_amdgcn_mfma_f32_16x16x32_bf16(v0, bpA0, oA0, 0, 0, 0);
    oB0 = __builtin_amdgcn_mfma_f32_16x16x32_bf16(v0, bpB0, oB0, 0, 0, 0);
    oA1 = __builtin_amdgcn_mfma_f32_16x16x32_bf16(v1, bpA0, oA1, 0, 0, 0);
    oB1 = __builtin_amdgcn_mfma_f32_16x16x32_bf16(v1, bpB0, oB1, 0, 0, 0);
    oA2 = __builtin_amdgcn_mfma_f32_16x16x32_bf16(v2, bpA0, oA2, 0, 0, 0);
    oB2 = __builtin_amdgcn_mfma_f32_16x16x32_bf16(v2, bpB0, oB2, 0, 0, 0);
    oA3 = __builtin_amdgcn_mfma_f32_16x16x32_bf16(v3, bpA0, oA3, 0, 0, 0);
    oB3 = __builtin_amdgcn_mfma_f32_16x16x32_bf16(v3, bpB0, oB3, 0, 0, 0);
    oA0 = __builtin_amdgcn_mfma_f32_16x16x32_bf16(v4, bpA1, oA0, 0, 0, 0);
    oB0 = __builtin_amdgcn_mfma_f32_16x16x32_bf16(v4, bpB1, oB0, 0, 0, 0);
    oA1 = __builtin_amdgcn_mfma_f32_16x16x32_bf16(v5, bpA1, oA1, 0, 0, 0);
    oB1 = __builtin_amdgcn_mfma_f32_16x16x32_bf16(v5, bpB1, oB1, 0, 0, 0);
    oA2 = __builtin_amdgcn_mfma_f32_16x16x32_bf16(v6, bpA1, oA2, 0, 0, 0);
    oB2 = __builtin_amdgcn_mfma_f32_16x16x32_bf16(v6, bpB1, oB2, 0, 0, 0);
    oA3 = __builtin_amdgcn_mfma_f32_16x16x32_bf16(v7, bpA1, oA3, 0, 0, 0);
    oB3 = __builtin_amdgcn_mfma_f32_16x16x32_bf16(v7, bpB1, oB3, 0, 0, 0);
    __builtin_amdgcn_s_setprio(0);

    // single end-of-trip sync: drains this wave's prefetch AND protects
    // buf[cur] reuse two trips from now.
    __syncthreads();
    cur ^= 1;
  }

  // reduce row sums across the 4 quads holding each q's kv slices
  lpA += __shfl_xor(lpA, 16);
  lpA += __shfl_xor(lpA, 32);
  lpB += __shfl_xor(lpB, 16);
  lpB += __shfl_xor(lpB, 32);
  const float ilA = 1.f / lpA;
  const float ilB = 1.f / lpB;

  // O^T: lane holds q=l15's d = db*16 + 4*quad + r  -> 4x ushort4 stores/group
  {
    unsigned short* ob = Qio + ((size_t)(b * SEQL + qrowA)) * DMODEL + h * DHEAD + quad * 4;
    ushort4 v;
    v.x = f2bf(oA0[0] * ilA); v.y = f2bf(oA0[1] * ilA);
    v.z = f2bf(oA0[2] * ilA); v.w = f2bf(oA0[3] * ilA);
    *(ushort4*)(ob) = v;
    v.x = f2bf(oA1[0] * ilA); v.y = f2bf(oA1[1] * ilA);
    v.z = f2bf(oA1[2] * ilA); v.w = f2bf(oA1[3] * ilA);
    *(ushort4*)(ob + 16) = v;
    v.x = f2bf(oA2[0] * ilA); v.y = f2bf(oA2[1] * ilA);
    v.z = f2bf(oA2[2] * ilA); v.w = f2bf(oA2[3] * ilA);
    *(ushort4*)(ob + 32) = v;
    v.x = f2bf(oA3[0] * ilA); v.y = f2bf(oA3[1] * ilA);
    v.z = f2bf(oA3[2] * ilA); v.w = f2bf(oA3[3] * ilA);
    *(ushort4*)(ob + 48) = v;
  }
  {
    unsigned short* ob = Qio + ((size_t)(b * SEQL + qrowB)) * DMODEL + h * DHEAD + quad * 4;
    ushort4 v;
    v.x = f2bf(oB0[0] * ilB); v.y = f2bf(oB0[1] * ilB);
    v.z = f2bf(oB0[2] * ilB); v.w = f2bf(oB0[3] * ilB);
    *(ushort4*)(ob) = v;
    v.x = f2bf(oB1[0] * ilB); v.y = f2bf(oB1[1] * ilB);
    v.z = f2bf(oB1[2] * ilB); v.w = f2bf(oB1[3] * ilB);
    *(ushort4*)(ob + 16) = v;
    v.x = f2bf(oB2[0] * ilB); v.y = f2bf(oB2[1] * ilB);
    v.z = f2bf(oB2[2] * ilB); v.w = f2bf(oB2[3] * ilB);
    *(ushort4*)(ob + 32) = v;
    v.x = f2bf(oB3[0] * ilB); v.y = f2bf(oB3[1] * ilB);
    v.z = f2bf(oB3[2] * ilB); v.w = f2bf(oB3[3] * ilB);
    *(ushort4*)(ob + 48) = v;
  }
}

// ---------------------------------------------------------------------------
extern "C" void kernel_launch(void* const* d_in, const int* in_sizes, int n_in,
                              void* d_out, int out_size, void* d_ws, size_t ws_size,
                              hipStream_t stream) {
  (void)in_sizes; (void)n_in; (void)out_size; (void)ws_size;
  const float* x  = (const float*)d_in[0];
  const int* tpos = (const int*)d_in[1];
  const float* Wq = (const float*)d_in[2];
  const float* Wk = (const float*)d_in[3];
  const float* Wv = (const float*)d_in[4];
  const float* Wo = (const float*)d_in[5];
  float* out      = (float*)d_out;

  char* ws = (char*)d_ws;
  const size_t MB = 1024 * 1024;
  unsigned short* Qf  = (unsigned short*)(ws);            // 8 MB
  unsigned short* Kf  = (unsigned short*)(ws + 8 * MB);   // 8 MB
  unsigned short* Vt  = (unsigned short*)(ws + 16 * MB);  // 8 MB
  unsigned short* xb  = (unsigned short*)(ws + 24 * MB);  // 8 MB
  unsigned short* wqb = (unsigned short*)(ws + 32 * MB);  // 2 MB
  unsigned short* wkb = (unsigned short*)(ws + 34 * MB);  // 2 MB
  unsigned short* wvb = (unsigned short*)(ws + 36 * MB);  // 2 MB
  unsigned short* wob = (unsigned short*)(ws + 38 * MB);  // 2 MB -> 40 MB total

  // one-shot fp32 -> bf16 conversion (x + 4 weights)
  cvt_bf16<<<dim3(512, 8), 256, 0, stream>>>(x, Wq, Wk, Wv, Wo, xb, wqb, wkb, wvb, wob);
  // Q,K,V projections (all-bf16, async staging; V written transposed)
  gemm_qkv<<<dim3(8, 32, 3), 256, 0, stream>>>(xb, wqb, wkb, wvb, Qf, Kf, Vt, MROWS, DMODEL, DMODEL);
  // RoPE in place on Q,K (Q pre-scaled by 0.125)
  rope_inplace<<<dim3(MROWS), 256, 0, stream>>>(Qf, Kf, tpos);
  // causal attention; 512 blocks (128 q rows each), heavy-first halves with
  // complementary per-CU pairing, XCD-swizzled bh
  attn_kernel<<<dim3(512), 256, 0, stream>>>(Kf, Vt, Qf);
  // output projection (bf16 A, bf16 W, fp32 out)
  gemm_out<<<dim3(8, 32, 1), 256, 0, stream>>>(Qf, wob, out, MROWS, DMODEL, DMODEL);
}